// Round 1
// baseline (499.602 us; speedup 1.0000x reference)
//
#include <hip/hip_runtime.h>

// Problem constants (fixed by the reference)
#define B_   32
#define T_   2048
#define IN_  1024
#define OUT_ 256
#define M_   (B_ * T_)   // 65536 rows

// GEMM tiling
#define BM 64
#define BN 64
#define BK 16

// Scan chunking
#define NC 16
#define LC (T_ / NC)     // 128

// ---------------------------------------------------------------------------
// GEMM: C[m, o] = sum_i A[m, i] * W[o, i] + bias[o]
// A: [M, IN] row-major, W: [OUT, IN] row-major (both contiguous along K) -> NT GEMM
// 64x64 tile, BK=16, 256 threads, 4x4 micro-tile per thread.
// ---------------------------------------------------------------------------
__global__ __launch_bounds__(256) void gemm_bias(const float* __restrict__ A,
                                                 const float* __restrict__ W,
                                                 const float* __restrict__ bias,
                                                 float* __restrict__ C) {
    __shared__ float As[BK][BM + 4];  // +4 floats keeps 16B alignment for float4 reads
    __shared__ float Ws[BK][BN + 4];

    const int bm = blockIdx.y * BM;
    const int bn = blockIdx.x * BN;
    const int tid = threadIdx.x;          // 0..255
    const int tx = tid & 15;              // N direction
    const int ty = tid >> 4;              // M direction
    const int lr = tid >> 2;              // 0..63: tile row for staging
    const int lc = (tid & 3) << 2;        // 0,4,8,12: k offset for staging (float4)

    float acc[4][4] = {};

    const float* Ap = A + (size_t)(bm + lr) * IN_ + lc;
    const float* Wp = W + (size_t)(bn + lr) * IN_ + lc;

    for (int k0 = 0; k0 < IN_; k0 += BK) {
        const float4 a = *(const float4*)(Ap + k0);
        const float4 w = *(const float4*)(Wp + k0);
        __syncthreads();  // previous iteration's LDS reads complete before overwrite
        As[lc + 0][lr] = a.x; As[lc + 1][lr] = a.y; As[lc + 2][lr] = a.z; As[lc + 3][lr] = a.w;
        Ws[lc + 0][lr] = w.x; Ws[lc + 1][lr] = w.y; Ws[lc + 2][lr] = w.z; Ws[lc + 3][lr] = w.w;
        __syncthreads();
#pragma unroll
        for (int kk = 0; kk < BK; ++kk) {
            const float4 av = *(const float4*)&As[kk][ty << 2];
            const float4 wv = *(const float4*)&Ws[kk][tx << 2];
            const float a0[4] = {av.x, av.y, av.z, av.w};
            const float w0[4] = {wv.x, wv.y, wv.z, wv.w};
#pragma unroll
            for (int i = 0; i < 4; ++i)
#pragma unroll
                for (int j = 0; j < 4; ++j)
                    acc[i][j] = fmaf(a0[i], w0[j], acc[i][j]);
        }
    }

#pragma unroll
    for (int i = 0; i < 4; ++i) {
        const size_t row = (size_t)(bm + (ty << 2) + i);
#pragma unroll
        for (int j = 0; j < 4; ++j) {
            const int col = bn + (tx << 2) + j;
            C[row * OUT_ + col] = acc[i][j] + bias[col];
        }
    }
}

// ---------------------------------------------------------------------------
// Chunked scan: u_t = alpha*u_{t-1} + (1-alpha)*x_t, u_0 = 0, over T per (b,o).
// Affine composition: u at chunk end = alpha^LC * u_at_chunk_start + local_end.
// pass1: per-chunk local scan (no stores of intermediates), record local_end.
// pass2: sequential carry across the NC chunk states (tiny).
// pass3: redo local scan seeded with carry, write final u in place over C.
// ---------------------------------------------------------------------------
__global__ __launch_bounds__(OUT_) void scan_pass1(const float* __restrict__ C,
                                                   const float* __restrict__ decay,
                                                   float* __restrict__ chunkend) {
    const int b = blockIdx.x / NC;
    const int c = blockIdx.x % NC;
    const int o = threadIdx.x;
    const float alpha = decay[o];
    const float om = 1.0f - alpha;
    const float* p = C + ((size_t)b * T_ + (size_t)c * LC) * OUT_ + o;
    float u = 0.0f;
#pragma unroll 4
    for (int t = 0; t < LC; ++t)
        u = fmaf(alpha, u, om * p[(size_t)t * OUT_]);
    chunkend[((size_t)b * NC + c) * OUT_ + o] = u;
}

__global__ __launch_bounds__(OUT_) void scan_pass2(const float* __restrict__ chunkend,
                                                   const float* __restrict__ decay,
                                                   float* __restrict__ carryin) {
    const int b = blockIdx.x;
    const int o = threadIdx.x;
    const float alpha = decay[o];
    const float aL = powf(alpha, (float)LC);
    float carry = 0.0f;
    for (int c = 0; c < NC; ++c) {
        const size_t idx = ((size_t)b * NC + c) * OUT_ + o;
        carryin[idx] = carry;
        carry = fmaf(aL, carry, chunkend[idx]);
    }
}

__global__ __launch_bounds__(OUT_) void scan_pass3(float* __restrict__ C,
                                                   const float* __restrict__ decay,
                                                   const float* __restrict__ carryin) {
    const int b = blockIdx.x / NC;
    const int c = blockIdx.x % NC;
    const int o = threadIdx.x;
    const float alpha = decay[o];
    const float om = 1.0f - alpha;
    float u = carryin[((size_t)b * NC + c) * OUT_ + o];
    float* p = C + ((size_t)b * T_ + (size_t)c * LC) * OUT_ + o;
#pragma unroll 4
    for (int t = 0; t < LC; ++t) {
        const float x = p[(size_t)t * OUT_];
        u = fmaf(alpha, u, om * x);
        p[(size_t)t * OUT_] = u;
    }
}

// Fallback: single-pass scan (used only if d_ws is too small for carries).
__global__ __launch_bounds__(OUT_) void scan_simple(float* __restrict__ C,
                                                    const float* __restrict__ decay) {
    const int b = blockIdx.x;
    const int o = threadIdx.x;
    const float alpha = decay[o];
    const float om = 1.0f - alpha;
    float u = 0.0f;
    float* p = C + (size_t)b * T_ * OUT_ + o;
    for (int t = 0; t < T_; ++t) {
        const float x = p[(size_t)t * OUT_];
        u = fmaf(alpha, u, om * x);
        p[(size_t)t * OUT_] = u;
    }
}

extern "C" void kernel_launch(void* const* d_in, const int* in_sizes, int n_in,
                              void* d_out, int out_size, void* d_ws, size_t ws_size,
                              hipStream_t stream) {
    const float* inputs = (const float*)d_in[0];
    const float* weight = (const float*)d_in[1];
    const float* bias   = (const float*)d_in[2];
    const float* decay  = (const float*)d_in[3];
    float* out = (float*)d_out;

    dim3 gemm_grid(OUT_ / BN, M_ / BM);  // (4, 1024)
    gemm_bias<<<gemm_grid, 256, 0, stream>>>(inputs, weight, bias, out);

    const size_t need = (size_t)2 * B_ * NC * OUT_ * sizeof(float);  // 1 MB
    if (ws_size >= need) {
        float* chunkend = (float*)d_ws;
        float* carryin  = chunkend + (size_t)B_ * NC * OUT_;
        scan_pass1<<<B_ * NC, OUT_, 0, stream>>>(out, decay, chunkend);
        scan_pass2<<<B_, OUT_, 0, stream>>>(chunkend, decay, carryin);
        scan_pass3<<<B_ * NC, OUT_, 0, stream>>>(out, decay, carryin);
    } else {
        scan_simple<<<B_, OUT_, 0, stream>>>(out, decay);
    }
}

// Round 3
// 136.000 us; speedup vs baseline: 3.6735x; 3.6735x over previous
//
#include <hip/hip_runtime.h>

// Problem constants
#define B_   32
#define T_   2048
#define IN_  1024
#define OUT_ 256
#define M_   (B_ * T_)   // 65536

// MFMA GEMM tiling: full-N block tile so A is read exactly once.
#define BM 128
#define BN 256
#define BK 64
#define NSTEPS (IN_ / BK)   // 16
#define THREADS 512

// Scan chunking
#define NC 16
#define LC (T_ / NC)        // 128

typedef __attribute__((ext_vector_type(4))) float f32x4;
typedef __attribute__((ext_vector_type(8))) __bf16 bf16x8;

// fp32 -> bf16 round-to-nearest-even, packed pair (b in hi, a in lo)
__device__ __forceinline__ unsigned int f2bf_pk(float a, float b) {
    unsigned int ua = __float_as_uint(a);
    unsigned int ub = __float_as_uint(b);
    ua = (ua + 0x7fffu + ((ua >> 16) & 1u)) >> 16;
    ub = (ub + 0x7fffu + ((ub >> 16) & 1u)) >> 16;
    return ua | (ub << 16);
}

// ---------------------------------------------------------------------------
// One-shot W fp32 -> bf16 into workspace (512 KB). 256 blocks x 256 thr x 4 elems.
// ---------------------------------------------------------------------------
__global__ __launch_bounds__(256) void convert_w(const float* __restrict__ W,
                                                 unsigned short* __restrict__ Wb) {
    const int i = blockIdx.x * 256 + threadIdx.x;  // float4 index
    const float4 v = ((const float4*)W)[i];
    uint2 o;
    o.x = f2bf_pk(v.x, v.y);
    o.y = f2bf_pk(v.z, v.w);
    ((uint2*)Wb)[i] = o;
}

// ---------------------------------------------------------------------------
// bf16 MFMA GEMM: C[m,o] = sum_k A[m,k]*W[o,k] + bias[o]
// A fp32 (converted in-register to bf16), W pre-converted bf16.
// LDS layout [row][k] in 16B granules, XOR-swizzled: slot = g ^ (row&7)
// -> ds_read_b128 fragment reads are <=2-way bank aliased (free).
// Double-buffered, one barrier per K-step, loads for step t+1 issued before
// compute of step t (write-late staging, T14 pattern).
// ---------------------------------------------------------------------------
__global__ __launch_bounds__(THREADS, 1) void gemm_mfma(
    const float* __restrict__ A, const unsigned short* __restrict__ Wb,
    const float* __restrict__ bias, float* __restrict__ C) {
    __shared__ __align__(16) unsigned short Abuf[2][BM * BK];  // 16 KB each
    __shared__ __align__(16) unsigned short Bbuf[2][BN * BK];  // 32 KB each

    const int tid  = threadIdx.x;
    const int lane = tid & 63;
    const int wid  = tid >> 6;
    const int wm   = wid >> 2;     // 0..1  (M direction)
    const int wn   = wid & 3;      // 0..3  (N direction)
    const int l15  = lane & 15;
    const int l4   = lane >> 4;    // 0..3
    const int bm0  = blockIdx.x * BM;

    // Staging geometry: granule = 8 elements (16B bf16). q -> (row=q>>3, g=q&7).
    const int gA = tid & 7;
    int rA[2], ldsA[2];
    const float* gsrcA[2];
#pragma unroll
    for (int i = 0; i < 2; ++i) {
        const int q = tid + i * THREADS;
        rA[i] = q >> 3;
        ldsA[i] = rA[i] * BK + ((gA ^ (rA[i] & 7)) << 3);
        gsrcA[i] = A + (size_t)(bm0 + rA[i]) * IN_ + gA * 8;
    }
    int ldsB[4];
    const unsigned short* gsrcB[4];
#pragma unroll
    for (int i = 0; i < 4; ++i) {
        const int q = tid + i * THREADS;
        const int r = q >> 3;
        ldsB[i] = r * BK + ((gA ^ (r & 7)) << 3);
        gsrcB[i] = Wb + (size_t)r * IN_ + gA * 8;
    }

    f32x4 acc[4][4] = {};
    float4 a0[2], a1[2];
    int4 bst[4];

    // --- prologue: stage tile 0 into buf 0 ---
#pragma unroll
    for (int i = 0; i < 2; ++i) {
        a0[i] = *(const float4*)(gsrcA[i]);
        a1[i] = *(const float4*)(gsrcA[i] + 4);
    }
#pragma unroll
    for (int i = 0; i < 4; ++i) bst[i] = *(const int4*)(gsrcB[i]);
#pragma unroll
    for (int i = 0; i < 2; ++i) {
        int4 w;
        w.x = f2bf_pk(a0[i].x, a0[i].y); w.y = f2bf_pk(a0[i].z, a0[i].w);
        w.z = f2bf_pk(a1[i].x, a1[i].y); w.w = f2bf_pk(a1[i].z, a1[i].w);
        *(int4*)&Abuf[0][ldsA[i]] = w;
    }
#pragma unroll
    for (int i = 0; i < 4; ++i) *(int4*)&Bbuf[0][ldsB[i]] = bst[i];
    __syncthreads();

    int cur = 0;
    for (int step = 0; step < NSTEPS; ++step) {
        const int nxt = step + 1;
        if (nxt < NSTEPS) {
            const int k0 = nxt * BK;
#pragma unroll
            for (int i = 0; i < 2; ++i) {
                a0[i] = *(const float4*)(gsrcA[i] + k0);
                a1[i] = *(const float4*)(gsrcA[i] + k0 + 4);
            }
#pragma unroll
            for (int i = 0; i < 4; ++i) bst[i] = *(const int4*)(gsrcB[i] + k0);
        }
        // compute on buf[cur]
#pragma unroll
        for (int ks = 0; ks < 2; ++ks) {
            bf16x8 af[4], bfv[4];
            const int kg = (ks << 2) + l4;
#pragma unroll
            for (int mi = 0; mi < 4; ++mi) {
                const int row = wm * 64 + mi * 16 + l15;
                af[mi] = *(const bf16x8*)&Abuf[cur][row * BK + ((kg ^ (row & 7)) << 3)];
            }
#pragma unroll
            for (int ni = 0; ni < 4; ++ni) {
                const int col = wn * 64 + ni * 16 + l15;
                bfv[ni] = *(const bf16x8*)&Bbuf[cur][col * BK + ((kg ^ (col & 7)) << 3)];
            }
#pragma unroll
            for (int mi = 0; mi < 4; ++mi)
#pragma unroll
                for (int ni = 0; ni < 4; ++ni)
                    acc[mi][ni] = __builtin_amdgcn_mfma_f32_16x16x32_bf16(
                        af[mi], bfv[ni], acc[mi][ni], 0, 0, 0);
        }
        if (nxt < NSTEPS) {
#pragma unroll
            for (int i = 0; i < 2; ++i) {
                int4 w;
                w.x = f2bf_pk(a0[i].x, a0[i].y); w.y = f2bf_pk(a0[i].z, a0[i].w);
                w.z = f2bf_pk(a1[i].x, a1[i].y); w.w = f2bf_pk(a1[i].z, a1[i].w);
                *(int4*)&Abuf[cur ^ 1][ldsA[i]] = w;
            }
#pragma unroll
            for (int i = 0; i < 4; ++i) *(int4*)&Bbuf[cur ^ 1][ldsB[i]] = bst[i];
        }
        __syncthreads();
        cur ^= 1;
    }

    // epilogue: bias + store (D frag: col=lane&15, row=(lane>>4)*4+r)
#pragma unroll
    for (int ni = 0; ni < 4; ++ni) {
        const int col = wn * 64 + ni * 16 + l15;
        const float bv = bias[col];
#pragma unroll
        for (int mi = 0; mi < 4; ++mi) {
            const int row0 = bm0 + wm * 64 + mi * 16 + (l4 << 2);
#pragma unroll
            for (int r = 0; r < 4; ++r)
                C[(size_t)(row0 + r) * OUT_ + col] = acc[mi][ni][r] + bv;
        }
    }
}

// ---------------------------------------------------------------------------
// Fallback fp32 GEMM (only if ws too small) — round-1 kernel, known good.
// ---------------------------------------------------------------------------
__global__ __launch_bounds__(256) void gemm_bias(const float* __restrict__ A,
                                                 const float* __restrict__ W,
                                                 const float* __restrict__ bias,
                                                 float* __restrict__ C) {
    __shared__ float As[16][64 + 4];
    __shared__ float Ws[16][64 + 4];
    const int bm = blockIdx.y * 64;
    const int bn = blockIdx.x * 64;
    const int tid = threadIdx.x;
    const int tx = tid & 15, ty = tid >> 4;
    const int lr = tid >> 2, lc = (tid & 3) << 2;
    float acc[4][4] = {};
    const float* Ap = A + (size_t)(bm + lr) * IN_ + lc;
    const float* Wp = W + (size_t)(bn + lr) * IN_ + lc;
    for (int k0 = 0; k0 < IN_; k0 += 16) {
        const float4 a = *(const float4*)(Ap + k0);
        const float4 w = *(const float4*)(Wp + k0);
        __syncthreads();
        As[lc + 0][lr] = a.x; As[lc + 1][lr] = a.y; As[lc + 2][lr] = a.z; As[lc + 3][lr] = a.w;
        Ws[lc + 0][lr] = w.x; Ws[lc + 1][lr] = w.y; Ws[lc + 2][lr] = w.z; Ws[lc + 3][lr] = w.w;
        __syncthreads();
#pragma unroll
        for (int kk = 0; kk < 16; ++kk) {
            const float4 av = *(const float4*)&As[kk][ty << 2];
            const float4 wv = *(const float4*)&Ws[kk][tx << 2];
            const float a0[4] = {av.x, av.y, av.z, av.w};
            const float w0[4] = {wv.x, wv.y, wv.z, wv.w};
#pragma unroll
            for (int i = 0; i < 4; ++i)
#pragma unroll
                for (int j = 0; j < 4; ++j) acc[i][j] = fmaf(a0[i], w0[j], acc[i][j]);
        }
    }
#pragma unroll
    for (int i = 0; i < 4; ++i) {
        const size_t row = (size_t)(bm + (ty << 2) + i);
#pragma unroll
        for (int j = 0; j < 4; ++j)
            C[row * OUT_ + bn + (tx << 2) + j] = acc[i][j] + bias[bn + (tx << 2) + j];
    }
}

// ---------------------------------------------------------------------------
// 3-pass chunked scan (unchanged from round 1)
// ---------------------------------------------------------------------------
__global__ __launch_bounds__(OUT_) void scan_pass1(const float* __restrict__ C,
                                                   const float* __restrict__ decay,
                                                   float* __restrict__ chunkend) {
    const int b = blockIdx.x / NC;
    const int c = blockIdx.x % NC;
    const int o = threadIdx.x;
    const float alpha = decay[o];
    const float om = 1.0f - alpha;
    const float* p = C + ((size_t)b * T_ + (size_t)c * LC) * OUT_ + o;
    float u = 0.0f;
#pragma unroll 4
    for (int t = 0; t < LC; ++t) u = fmaf(alpha, u, om * p[(size_t)t * OUT_]);
    chunkend[((size_t)b * NC + c) * OUT_ + o] = u;
}

__global__ __launch_bounds__(OUT_) void scan_pass2(const float* __restrict__ chunkend,
                                                   const float* __restrict__ decay,
                                                   float* __restrict__ carryin) {
    const int b = blockIdx.x;
    const int o = threadIdx.x;
    const float alpha = decay[o];
    const float aL = powf(alpha, (float)LC);
    float carry = 0.0f;
    for (int c = 0; c < NC; ++c) {
        const size_t idx = ((size_t)b * NC + c) * OUT_ + o;
        carryin[idx] = carry;
        carry = fmaf(aL, carry, chunkend[idx]);
    }
}

__global__ __launch_bounds__(OUT_) void scan_pass3(float* __restrict__ C,
                                                   const float* __restrict__ decay,
                                                   const float* __restrict__ carryin) {
    const int b = blockIdx.x / NC;
    const int c = blockIdx.x % NC;
    const int o = threadIdx.x;
    const float alpha = decay[o];
    const float om = 1.0f - alpha;
    float u = carryin[((size_t)b * NC + c) * OUT_ + o];
    float* p = C + ((size_t)b * T_ + (size_t)c * LC) * OUT_ + o;
#pragma unroll 4
    for (int t = 0; t < LC; ++t) {
        const float x = p[(size_t)t * OUT_];
        u = fmaf(alpha, u, om * x);
        p[(size_t)t * OUT_] = u;
    }
}

__global__ __launch_bounds__(OUT_) void scan_simple(float* __restrict__ C,
                                                    const float* __restrict__ decay) {
    const int b = blockIdx.x;
    const int o = threadIdx.x;
    const float alpha = decay[o];
    const float om = 1.0f - alpha;
    float u = 0.0f;
    float* p = C + (size_t)b * T_ * OUT_ + o;
    for (int t = 0; t < T_; ++t) {
        const float x = p[(size_t)t * OUT_];
        u = fmaf(alpha, u, om * x);
        p[(size_t)t * OUT_] = u;
    }
}

extern "C" void kernel_launch(void* const* d_in, const int* in_sizes, int n_in,
                              void* d_out, int out_size, void* d_ws, size_t ws_size,
                              hipStream_t stream) {
    const float* inputs = (const float*)d_in[0];
    const float* weight = (const float*)d_in[1];
    const float* bias   = (const float*)d_in[2];
    const float* decay  = (const float*)d_in[3];
    float* out = (float*)d_out;

    const size_t wbytes = (size_t)OUT_ * IN_ * 2;              // 512 KB bf16 W
    const size_t sbytes = (size_t)2 * B_ * NC * OUT_ * 4;      // 1 MB scan carries

    if (ws_size >= wbytes + sbytes) {
        unsigned short* Wb = (unsigned short*)d_ws;
        float* chunkend = (float*)((char*)d_ws + wbytes);
        float* carryin  = chunkend + (size_t)B_ * NC * OUT_;

        convert_w<<<(OUT_ * IN_ / 4) / 256, 256, 0, stream>>>(weight, Wb);
        gemm_mfma<<<M_ / BM, THREADS, 0, stream>>>(inputs, Wb, bias, out);
        scan_pass1<<<B_ * NC, OUT_, 0, stream>>>(out, decay, chunkend);
        scan_pass2<<<B_, OUT_, 0, stream>>>(chunkend, decay, carryin);
        scan_pass3<<<B_ * NC, OUT_, 0, stream>>>(out, decay, carryin);
    } else {
        dim3 g(OUT_ / 64, M_ / 64);
        gemm_bias<<<g, 256, 0, stream>>>(inputs, weight, bias, out);
        scan_simple<<<B_, OUT_, 0, stream>>>(out, decay);
    }
}

// Round 4
// 121.113 us; speedup vs baseline: 4.1251x; 1.1229x over previous
//
#include <hip/hip_runtime.h>

// Problem constants
#define B_   32
#define T_   2048
#define IN_  1024
#define OUT_ 256
#define M_   (B_ * T_)   // 65536

// MFMA GEMM tiling: full-N block tile so A is read exactly once.
#define BM 128
#define BN 256
#define BK 64
#define NSTEPS (IN_ / BK)   // 16
#define THREADS 512

// Scan chunking: LC=32 so one BM=128 GEMM block covers exactly 4 chunks.
#define LC 32
#define NC (T_ / LC)        // 64 chunks per batch
#define XPAD 264            // LDS x-tile row pitch (bf16 elems), 528B rows (16B-aligned)

typedef __attribute__((ext_vector_type(4))) float f32x4;
typedef __attribute__((ext_vector_type(8))) __bf16 bf16x8;

// fp32 -> bf16 round-to-nearest-even
__device__ __forceinline__ unsigned int f2bf_pk(float a, float b) {
    unsigned int ua = __float_as_uint(a);
    unsigned int ub = __float_as_uint(b);
    ua = (ua + 0x7fffu + ((ua >> 16) & 1u)) >> 16;
    ub = (ub + 0x7fffu + ((ub >> 16) & 1u)) >> 16;
    return ua | (ub << 16);
}
__device__ __forceinline__ unsigned short f2bf1(float a) {
    unsigned int ua = __float_as_uint(a);
    return (unsigned short)((ua + 0x7fffu + ((ua >> 16) & 1u)) >> 16);
}
__device__ __forceinline__ float bf2f(unsigned short s) {
    return __uint_as_float((unsigned int)s << 16);
}

// ---------------------------------------------------------------------------
// One-shot W fp32 -> bf16 into workspace (512 KB).
// ---------------------------------------------------------------------------
__global__ __launch_bounds__(256) void convert_w(const float* __restrict__ W,
                                                 unsigned short* __restrict__ Wb) {
    const int i = blockIdx.x * 256 + threadIdx.x;  // float4 index
    const float4 v = ((const float4*)W)[i];
    uint2 o;
    o.x = f2bf_pk(v.x, v.y);
    o.y = f2bf_pk(v.z, v.w);
    ((uint2*)Wb)[i] = o;
}

// ---------------------------------------------------------------------------
// Fused bf16 MFMA GEMM + chunk-local scan.
//   x[m,o] = sum_k A[m,k]*W[o,k] + bias[o]   (bf16-rounded)
// Epilogue: x tile -> LDS (bf16), dump x to ws (bf16, coalesced short8),
// per-chunk local leaky-integrator scan (seed 0) -> chunkend to ws.
// GEMM core identical to the round-3 verified kernel (XOR-swizzled LDS,
// double-buffered, one barrier per K-step, write-late staging).
// ---------------------------------------------------------------------------
__global__ __launch_bounds__(THREADS, 1) void gemm_fused(
    const float* __restrict__ A, const unsigned short* __restrict__ Wb,
    const float* __restrict__ bias, const float* __restrict__ decay,
    unsigned short* __restrict__ Xb, float* __restrict__ chunkend) {
    __shared__ __align__(16) char smem[98304];  // 96 KB: staging; reused for x tile
#define ABUF(c) ((unsigned short*)(smem + (c) * 16384))
#define BBUF(c) ((unsigned short*)(smem + 32768 + (c) * 32768))

    const int tid  = threadIdx.x;
    const int lane = tid & 63;
    const int wid  = tid >> 6;
    const int wm   = wid >> 2;     // 0..1  (M direction)
    const int wn   = wid & 3;      // 0..3  (N direction)
    const int l15  = lane & 15;
    const int l4   = lane >> 4;    // 0..3
    const int bm0  = blockIdx.x * BM;

    // Staging geometry: granule = 8 elements (16B bf16). q -> (row=q>>3, g=q&7).
    const int gA = tid & 7;
    int rA[2], ldsA[2];
    const float* gsrcA[2];
#pragma unroll
    for (int i = 0; i < 2; ++i) {
        const int q = tid + i * THREADS;
        rA[i] = q >> 3;
        ldsA[i] = rA[i] * BK + ((gA ^ (rA[i] & 7)) << 3);
        gsrcA[i] = A + (size_t)(bm0 + rA[i]) * IN_ + gA * 8;
    }
    int ldsB[4];
    const unsigned short* gsrcB[4];
#pragma unroll
    for (int i = 0; i < 4; ++i) {
        const int q = tid + i * THREADS;
        const int r = q >> 3;
        ldsB[i] = r * BK + ((gA ^ (r & 7)) << 3);
        gsrcB[i] = Wb + (size_t)r * IN_ + gA * 8;
    }

    f32x4 acc[4][4] = {};
    float4 a0[2], a1[2];
    int4 bst[4];

    // --- prologue: stage tile 0 into buf 0 ---
#pragma unroll
    for (int i = 0; i < 2; ++i) {
        a0[i] = *(const float4*)(gsrcA[i]);
        a1[i] = *(const float4*)(gsrcA[i] + 4);
    }
#pragma unroll
    for (int i = 0; i < 4; ++i) bst[i] = *(const int4*)(gsrcB[i]);
#pragma unroll
    for (int i = 0; i < 2; ++i) {
        int4 w;
        w.x = f2bf_pk(a0[i].x, a0[i].y); w.y = f2bf_pk(a0[i].z, a0[i].w);
        w.z = f2bf_pk(a1[i].x, a1[i].y); w.w = f2bf_pk(a1[i].z, a1[i].w);
        *(int4*)&ABUF(0)[ldsA[i]] = w;
    }
#pragma unroll
    for (int i = 0; i < 4; ++i) *(int4*)&BBUF(0)[ldsB[i]] = bst[i];
    __syncthreads();

    int cur = 0;
    for (int step = 0; step < NSTEPS; ++step) {
        const int nxt = step + 1;
        if (nxt < NSTEPS) {
            const int k0 = nxt * BK;
#pragma unroll
            for (int i = 0; i < 2; ++i) {
                a0[i] = *(const float4*)(gsrcA[i] + k0);
                a1[i] = *(const float4*)(gsrcA[i] + k0 + 4);
            }
#pragma unroll
            for (int i = 0; i < 4; ++i) bst[i] = *(const int4*)(gsrcB[i] + k0);
        }
        // compute on buf[cur]
#pragma unroll
        for (int ks = 0; ks < 2; ++ks) {
            bf16x8 af[4], bfv[4];
            const int kg = (ks << 2) + l4;
#pragma unroll
            for (int mi = 0; mi < 4; ++mi) {
                const int row = wm * 64 + mi * 16 + l15;
                af[mi] = *(const bf16x8*)&ABUF(cur)[row * BK + ((kg ^ (row & 7)) << 3)];
            }
#pragma unroll
            for (int ni = 0; ni < 4; ++ni) {
                const int col = wn * 64 + ni * 16 + l15;
                bfv[ni] = *(const bf16x8*)&BBUF(cur)[col * BK + ((kg ^ (col & 7)) << 3)];
            }
#pragma unroll
            for (int mi = 0; mi < 4; ++mi)
#pragma unroll
                for (int ni = 0; ni < 4; ++ni)
                    acc[mi][ni] = __builtin_amdgcn_mfma_f32_16x16x32_bf16(
                        af[mi], bfv[ni], acc[mi][ni], 0, 0, 0);
        }
        if (nxt < NSTEPS) {
#pragma unroll
            for (int i = 0; i < 2; ++i) {
                int4 w;
                w.x = f2bf_pk(a0[i].x, a0[i].y); w.y = f2bf_pk(a0[i].z, a0[i].w);
                w.z = f2bf_pk(a1[i].x, a1[i].y); w.w = f2bf_pk(a1[i].z, a1[i].w);
                *(int4*)&ABUF(cur ^ 1)[ldsA[i]] = w;
            }
#pragma unroll
            for (int i = 0; i < 4; ++i) *(int4*)&BBUF(cur ^ 1)[ldsB[i]] = bst[i];
        }
        __syncthreads();
        cur ^= 1;
    }
    // last iteration ended with __syncthreads(): staging buffers are dead now.

    // --- epilogue part 1: x = acc + bias -> bf16 into LDS tile [128][XPAD] ---
    unsigned short* xt = (unsigned short*)smem;
#pragma unroll
    for (int ni = 0; ni < 4; ++ni) {
        const int col = wn * 64 + ni * 16 + l15;
        const float bv = bias[col];
#pragma unroll
        for (int mi = 0; mi < 4; ++mi) {
            const int r0 = wm * 64 + mi * 16 + (l4 << 2);
#pragma unroll
            for (int r = 0; r < 4; ++r)
                xt[(r0 + r) * XPAD + col] = f2bf1(acc[mi][ni][r] + bv);
        }
    }
    __syncthreads();

    const int b  = bm0 >> 11;          // batch index (T = 2048)
    const int c0 = (bm0 >> 5) & 63;    // first chunk id within batch (LC = 32)

    // --- epilogue part 2: dump x tile to global ws (coalesced short8) ---
    {
        const int cr = tid >> 5;             // 0..15 (row within 16-row group)
        const int cg = (tid & 31) << 3;      // col (8-col granule)
#pragma unroll
        for (int it = 0; it < 8; ++it) {
            const int row = it * 16 + cr;
            bf16x8 v = *(const bf16x8*)&xt[row * XPAD + cg];
            *(bf16x8*)&Xb[(size_t)(bm0 + row) * OUT_ + cg] = v;
        }
    }

    // --- epilogue part 3: chunk-local scans (seed 0) -> chunkend ---
    // 4 chunks x 256 cols = 1024 tasks, 2 per thread. Same bf16 x values the
    // final scan will re-read -> carry composition is consistent.
    for (int task = tid; task < 4 * OUT_; task += THREADS) {
        const int cl  = task >> 8;       // 0..3 chunk within block
        const int col = task & 255;
        const float alpha = decay[col];
        const float om = 1.0f - alpha;
        float u = 0.0f;
        const unsigned short* p = &xt[(cl * LC) * XPAD + col];
#pragma unroll
        for (int t = 0; t < LC; ++t)
            u = fmaf(alpha, u, om * bf2f(p[t * XPAD]));
        chunkend[(size_t)(b * NC + c0 + cl) * OUT_ + col] = u;
    }
#undef ABUF
#undef BBUF
}

// ---------------------------------------------------------------------------
// Carry pass: sequential fold of the NC=64 chunkends per batch (tiny).
// u_chunkstart = carryin; u_end = alpha^LC * u_start + chunkend_local.
// ---------------------------------------------------------------------------
__global__ __launch_bounds__(OUT_) void carry_pass(const float* __restrict__ chunkend,
                                                   const float* __restrict__ decay,
                                                   float* __restrict__ carryin) {
    const int b = blockIdx.x;
    const int o = threadIdx.x;
    const float alpha = decay[o];
    float aL = alpha;
#pragma unroll
    for (int i = 1; i < LC; ++i) aL *= alpha;   // alpha^LC
    float carry = 0.0f;
    for (int c = 0; c < NC; ++c) {
        const size_t idx = (size_t)(b * NC + c) * OUT_ + o;
        carryin[idx] = carry;
        carry = fmaf(aL, carry, chunkend[idx]);
    }
}

// ---------------------------------------------------------------------------
// Final scan: 2048 independent (b,chunk) wave-units, 4 cols/thread.
// Reads bf16 x (short4, 512B/row/unit), writes fp32 u (float4, 1KB/row/unit).
// ---------------------------------------------------------------------------
__global__ __launch_bounds__(256) void scan_final(const unsigned short* __restrict__ Xb,
                                                  const float* __restrict__ decay,
                                                  const float* __restrict__ carryin,
                                                  float* __restrict__ out) {
    const int unit = blockIdx.x * 4 + (threadIdx.x >> 6);  // 0..2047 == b*NC + c
    const int l    = threadIdx.x & 63;
    const int col  = l << 2;
    const int b    = unit >> 6;
    const int c    = unit & 63;

    const float4 al = *(const float4*)&decay[col];
    const float4 om = {1.0f - al.x, 1.0f - al.y, 1.0f - al.z, 1.0f - al.w};
    float4 u = *(const float4*)&carryin[(size_t)unit * OUT_ + col];

    const size_t base = (size_t)(b * T_ + c * LC) * OUT_ + col;
#pragma unroll 4
    for (int t = 0; t < LC; ++t) {
        const ushort4 xv = *(const ushort4*)&Xb[base + (size_t)t * OUT_];
        u.x = fmaf(al.x, u.x, om.x * bf2f(xv.x));
        u.y = fmaf(al.y, u.y, om.y * bf2f(xv.y));
        u.z = fmaf(al.z, u.z, om.z * bf2f(xv.z));
        u.w = fmaf(al.w, u.w, om.w * bf2f(xv.w));
        *(float4*)&out[base + (size_t)t * OUT_] = u;
    }
}

// ---------------------------------------------------------------------------
// Fallback path (ws too small): round-1 fp32 GEMM + simple scan, known good.
// ---------------------------------------------------------------------------
__global__ __launch_bounds__(256) void gemm_bias(const float* __restrict__ A,
                                                 const float* __restrict__ W,
                                                 const float* __restrict__ bias,
                                                 float* __restrict__ C) {
    __shared__ float As[16][64 + 4];
    __shared__ float Ws[16][64 + 4];
    const int bm = blockIdx.y * 64;
    const int bn = blockIdx.x * 64;
    const int tid = threadIdx.x;
    const int tx = tid & 15, ty = tid >> 4;
    const int lr = tid >> 2, lc = (tid & 3) << 2;
    float acc[4][4] = {};
    const float* Ap = A + (size_t)(bm + lr) * IN_ + lc;
    const float* Wp = W + (size_t)(bn + lr) * IN_ + lc;
    for (int k0 = 0; k0 < IN_; k0 += 16) {
        const float4 a = *(const float4*)(Ap + k0);
        const float4 w = *(const float4*)(Wp + k0);
        __syncthreads();
        As[lc + 0][lr] = a.x; As[lc + 1][lr] = a.y; As[lc + 2][lr] = a.z; As[lc + 3][lr] = a.w;
        Ws[lc + 0][lr] = w.x; Ws[lc + 1][lr] = w.y; Ws[lc + 2][lr] = w.z; Ws[lc + 3][lr] = w.w;
        __syncthreads();
#pragma unroll
        for (int kk = 0; kk < 16; ++kk) {
            const float4 av = *(const float4*)&As[kk][ty << 2];
            const float4 wv = *(const float4*)&Ws[kk][tx << 2];
            const float a0[4] = {av.x, av.y, av.z, av.w};
            const float w0[4] = {wv.x, wv.y, wv.z, wv.w};
#pragma unroll
            for (int i = 0; i < 4; ++i)
#pragma unroll
                for (int j = 0; j < 4; ++j) acc[i][j] = fmaf(a0[i], w0[j], acc[i][j]);
        }
    }
#pragma unroll
    for (int i = 0; i < 4; ++i) {
        const size_t row = (size_t)(bm + (ty << 2) + i);
#pragma unroll
        for (int j = 0; j < 4; ++j)
            C[row * OUT_ + bn + (tx << 2) + j] = acc[i][j] + bias[bn + (tx << 2) + j];
    }
}

__global__ __launch_bounds__(OUT_) void scan_simple(float* __restrict__ C,
                                                    const float* __restrict__ decay) {
    const int b = blockIdx.x;
    const int o = threadIdx.x;
    const float alpha = decay[o];
    const float om = 1.0f - alpha;
    float u = 0.0f;
    float* p = C + (size_t)b * T_ * OUT_ + o;
    for (int t = 0; t < T_; ++t) {
        const float x = p[(size_t)t * OUT_];
        u = fmaf(alpha, u, om * x);
        p[(size_t)t * OUT_] = u;
    }
}

extern "C" void kernel_launch(void* const* d_in, const int* in_sizes, int n_in,
                              void* d_out, int out_size, void* d_ws, size_t ws_size,
                              hipStream_t stream) {
    const float* inputs = (const float*)d_in[0];
    const float* weight = (const float*)d_in[1];
    const float* bias   = (const float*)d_in[2];
    const float* decay  = (const float*)d_in[3];
    float* out = (float*)d_out;

    // Workspace layout
    const size_t wb_bytes = (size_t)OUT_ * IN_ * 2;             // 512 KB bf16 W
    const size_t ce_bytes = (size_t)B_ * NC * OUT_ * 4;         // 2 MB chunkend
    const size_t ci_bytes = ce_bytes;                           // 2 MB carryin
    const size_t x_bytes  = (size_t)M_ * OUT_ * 2;              // 32 MB bf16 x
    const size_t need = wb_bytes + ce_bytes + ci_bytes + x_bytes;

    if (ws_size >= need) {
        char* w = (char*)d_ws;
        unsigned short* Wb = (unsigned short*)w;
        float* chunkend    = (float*)(w + wb_bytes);
        float* carryin     = (float*)(w + wb_bytes + ce_bytes);
        unsigned short* Xb = (unsigned short*)(w + wb_bytes + ce_bytes + ci_bytes);

        convert_w<<<(OUT_ * IN_ / 4) / 256, 256, 0, stream>>>(weight, Wb);
        gemm_fused<<<M_ / BM, THREADS, 0, stream>>>(inputs, Wb, bias, decay, Xb, chunkend);
        carry_pass<<<B_, OUT_, 0, stream>>>(chunkend, decay, carryin);
        scan_final<<<(B_ * NC) / 4, 256, 0, stream>>>(Xb, decay, carryin, out);
    } else {
        dim3 g(OUT_ / 64, M_ / 64);
        gemm_bias<<<g, 256, 0, stream>>>(inputs, weight, bias, out);
        scan_simple<<<B_, OUT_, 0, stream>>>(out, decay);
    }
}

// Round 6
// 116.664 us; speedup vs baseline: 4.2824x; 1.0381x over previous
//
#include <hip/hip_runtime.h>

// Problem constants
#define B_   32
#define T_   2048
#define IN_  1024
#define OUT_ 256
#define M_   (B_ * T_)   // 65536

// MFMA GEMM tiling: full-N block tile so A is read exactly once.
// BK=32 + global_load_lds for B -> 66 KB LDS, 2 blocks/CU (16 waves/CU).
#define BM 128
#define BN 256
#define BK 32
#define NSTEPS (IN_ / BK)   // 32
#define THREADS 512

// Scan chunking: LC=32 so one BM=128 GEMM block covers exactly 4 chunks.
#define LC 32
#define NC (T_ / LC)        // 64 chunks per batch
#define XPAD 264            // LDS x-tile row pitch (bf16), 528B rows (16B-aligned)

// LDS: staging = 2*(128*32 + 256*32)*2B = 48 KB ; x-tile = 128*264*2 = 66 KB
#define SMEM_BYTES (BM * XPAD * 2)          // 67584, >= 49152 staging
#define ABUF_OFF(c) ((c) * (BM * BK * 2))                   // 8 KB each
#define BBUF_OFF(c) (2 * (BM * BK * 2) + (c) * (BN * BK * 2))  // 16 KB each

typedef __attribute__((ext_vector_type(4))) float f32x4;
typedef __attribute__((ext_vector_type(8))) __bf16 bf16x8;

// fp32 -> bf16 round-to-nearest-even
__device__ __forceinline__ unsigned int f2bf_pk(float a, float b) {
    unsigned int ua = __float_as_uint(a);
    unsigned int ub = __float_as_uint(b);
    ua = (ua + 0x7fffu + ((ua >> 16) & 1u)) >> 16;
    ub = (ub + 0x7fffu + ((ub >> 16) & 1u)) >> 16;
    return ua | (ub << 16);
}
__device__ __forceinline__ unsigned short f2bf1(float a) {
    unsigned int ua = __float_as_uint(a);
    return (unsigned short)((ua + 0x7fffu + ((ua >> 16) & 1u)) >> 16);
}
__device__ __forceinline__ float bf2f(unsigned short s) {
    return __uint_as_float((unsigned int)s << 16);
}

// async global -> LDS, 16B per lane; lds dest = wave-uniform base + lane*16
__device__ __forceinline__ void gload_lds16(const void* g, void* l) {
    __builtin_amdgcn_global_load_lds(
        (const __attribute__((address_space(1))) void*)g,
        (__attribute__((address_space(3))) void*)l, 16, 0, 0);
}

// ---------------------------------------------------------------------------
// One-shot W fp32 -> bf16 into workspace (512 KB).
// ---------------------------------------------------------------------------
__global__ __launch_bounds__(256) void convert_w(const float* __restrict__ W,
                                                 unsigned short* __restrict__ Wb) {
    const int i = blockIdx.x * 256 + threadIdx.x;  // float4 index
    const float4 v = ((const float4*)W)[i];
    uint2 o;
    o.x = f2bf_pk(v.x, v.y);
    o.y = f2bf_pk(v.z, v.w);
    ((uint2*)Wb)[i] = o;
}

// ---------------------------------------------------------------------------
// Fused bf16 MFMA GEMM + chunk-local scan.
// A reg-staged (fp32->bf16 pack), B via global_load_lds with pre-swizzled
// global source (linear LDS dest + XOR'd source granule == XOR'd read, m201).
// Double-buffered, one barrier per K-step, 2 blocks/CU.
// ---------------------------------------------------------------------------
__global__ __launch_bounds__(THREADS, 4) void gemm_fused(
    const float* __restrict__ A, const unsigned short* __restrict__ Wb,
    const float* __restrict__ bias, const float* __restrict__ decay,
    unsigned short* __restrict__ Xb, float* __restrict__ chunkend) {
    __shared__ __align__(16) char smem[SMEM_BYTES];

    const int tid  = threadIdx.x;
    const int lane = tid & 63;
    const int wid  = tid >> 6;
    const int wm   = wid >> 2;     // 0..1  (M direction)
    const int wn   = wid & 3;      // 0..3  (N direction)
    const int l15  = lane & 15;
    const int l4   = lane >> 4;    // 0..3
    const int bm0  = blockIdx.x * BM;

    // --- A staging: 1 granule (8 elems) per thread. q=tid -> row=q>>2, g=q&3.
    const int rowA = tid >> 2;
    const int gA   = tid & 3;
    const float* gsrcA = A + (size_t)(bm0 + rowA) * IN_ + gA * 8;
    const int ldsA = rowA * BK + ((gA ^ (rowA & 3)) << 3);   // elements

    // --- B staging via global_load_lds: 2 instrs/wave, linear LDS dest.
    // LDS granule q = (wid + i*8)*64 + lane -> row=q>>2, g_lin=q&3.
    // Source granule = g_lin ^ (row&3) (involution; read uses same XOR).
    const unsigned short* gsrcB[2];
    int ldsBbase[2];   // byte offset of wave-uniform LDS dest (within Bbuf)
#pragma unroll
    for (int i = 0; i < 2; ++i) {
        const int q = (wid + i * 8) * 64 + lane;
        const int r = q >> 2;
        const int g = (q & 3) ^ (r & 3);
        gsrcB[i] = Wb + (size_t)r * IN_ + g * 8;
        ldsBbase[i] = (wid + i * 8) * 1024;   // bytes; +lane*16 added by HW
    }

    f32x4 acc[4][4] = {};
    float4 a0, a1;

    // --- prologue: stage tile 0 into buf 0 ---
#pragma unroll
    for (int i = 0; i < 2; ++i)
        gload_lds16(gsrcB[i], smem + BBUF_OFF(0) + ldsBbase[i]);
    a0 = *(const float4*)(gsrcA);
    a1 = *(const float4*)(gsrcA + 4);
    {
        int4 w;
        w.x = f2bf_pk(a0.x, a0.y); w.y = f2bf_pk(a0.z, a0.w);
        w.z = f2bf_pk(a1.x, a1.y); w.w = f2bf_pk(a1.z, a1.w);
        *(int4*)(smem + ABUF_OFF(0) + ldsA * 2) = w;
    }
    __syncthreads();

    int cur = 0;
    for (int step = 0; step < NSTEPS; ++step) {
        const int nxt = step + 1;
        if (nxt < NSTEPS) {
            const int k0 = nxt * BK;
#pragma unroll
            for (int i = 0; i < 2; ++i)
                gload_lds16(gsrcB[i] + k0, smem + BBUF_OFF(cur ^ 1) + ldsBbase[i]);
            a0 = *(const float4*)(gsrcA + k0);
            a1 = *(const float4*)(gsrcA + k0 + 4);
        }
        // compute on buf[cur]
        {
            const unsigned short* Ab = (const unsigned short*)(smem + ABUF_OFF(cur));
            const unsigned short* Bb = (const unsigned short*)(smem + BBUF_OFF(cur));
            bf16x8 af[4], bfv[4];
#pragma unroll
            for (int mi = 0; mi < 4; ++mi) {
                const int row = wm * 64 + mi * 16 + l15;
                af[mi] = *(const bf16x8*)&Ab[row * BK + ((l4 ^ (row & 3)) << 3)];
            }
#pragma unroll
            for (int ni = 0; ni < 4; ++ni) {
                const int col = wn * 64 + ni * 16 + l15;
                bfv[ni] = *(const bf16x8*)&Bb[col * BK + ((l4 ^ (col & 3)) << 3)];
            }
#pragma unroll
            for (int mi = 0; mi < 4; ++mi)
#pragma unroll
                for (int ni = 0; ni < 4; ++ni)
                    acc[mi][ni] = __builtin_amdgcn_mfma_f32_16x16x32_bf16(
                        af[mi], bfv[ni], acc[mi][ni], 0, 0, 0);
        }
        if (nxt < NSTEPS) {
            int4 w;
            w.x = f2bf_pk(a0.x, a0.y); w.y = f2bf_pk(a0.z, a0.w);
            w.z = f2bf_pk(a1.x, a1.y); w.w = f2bf_pk(a1.z, a1.w);
            *(int4*)(smem + ABUF_OFF(cur ^ 1) + ldsA * 2) = w;
        }
        __syncthreads();
        cur ^= 1;
    }
    // staging buffers dead now (last iteration ended with a barrier).

    // --- epilogue part 1: x = acc + bias -> bf16 into LDS tile [128][XPAD] ---
    unsigned short* xt = (unsigned short*)smem;
#pragma unroll
    for (int ni = 0; ni < 4; ++ni) {
        const int col = wn * 64 + ni * 16 + l15;
        const float bv = bias[col];
#pragma unroll
        for (int mi = 0; mi < 4; ++mi) {
            const int r0 = wm * 64 + mi * 16 + (l4 << 2);
#pragma unroll
            for (int r = 0; r < 4; ++r)
                xt[(r0 + r) * XPAD + col] = f2bf1(acc[mi][ni][r] + bv);
        }
    }
    __syncthreads();

    const int b  = bm0 >> 11;          // batch index (T = 2048)
    const int c0 = (bm0 >> 5) & 63;    // first chunk id within batch (LC = 32)

    // --- epilogue part 2: dump x tile to global ws (coalesced short8) ---
    {
        const int cr = tid >> 5;             // 0..15
        const int cg = (tid & 31) << 3;      // 8-col granule
#pragma unroll
        for (int it = 0; it < 8; ++it) {
            const int row = it * 16 + cr;
            bf16x8 v = *(const bf16x8*)&xt[row * XPAD + cg];
            *(bf16x8*)&Xb[(size_t)(bm0 + row) * OUT_ + cg] = v;
        }
    }

    // --- epilogue part 3: chunk-local scans (seed 0) -> chunkend ---
    for (int task = tid; task < 4 * OUT_; task += THREADS) {
        const int cl  = task >> 8;       // 0..3 chunk within block
        const int col = task & 255;
        const float alpha = decay[col];
        const float om = 1.0f - alpha;
        float u = 0.0f;
        const unsigned short* p = &xt[(cl * LC) * XPAD + col];
#pragma unroll
        for (int t = 0; t < LC; ++t)
            u = fmaf(alpha, u, om * bf2f(p[t * XPAD]));
        chunkend[(size_t)(b * NC + c0 + cl) * OUT_ + col] = u;
    }
}

// ---------------------------------------------------------------------------
// Carry pass: sequential fold of the NC=64 chunkends per batch (tiny).
// ---------------------------------------------------------------------------
__global__ __launch_bounds__(OUT_) void carry_pass(const float* __restrict__ chunkend,
                                                   const float* __restrict__ decay,
                                                   float* __restrict__ carryin) {
    const int b = blockIdx.x;
    const int o = threadIdx.x;
    const float alpha = decay[o];
    float aL = alpha;
#pragma unroll
    for (int i = 1; i < LC; ++i) aL *= alpha;   // alpha^LC
    float carry = 0.0f;
    for (int c = 0; c < NC; ++c) {
        const size_t idx = (size_t)(b * NC + c) * OUT_ + o;
        carryin[idx] = carry;
        carry = fmaf(aL, carry, chunkend[idx]);
    }
}

// ---------------------------------------------------------------------------
// Final scan: 2048 independent (b,chunk) wave-units, 4 cols/thread.
// ---------------------------------------------------------------------------
__global__ __launch_bounds__(256) void scan_final(const unsigned short* __restrict__ Xb,
                                                  const float* __restrict__ decay,
                                                  const float* __restrict__ carryin,
                                                  float* __restrict__ out) {
    const int unit = blockIdx.x * 4 + (threadIdx.x >> 6);  // == b*NC + c
    const int l    = threadIdx.x & 63;
    const int col  = l << 2;
    const int b    = unit >> 6;
    const int c    = unit & 63;

    const float4 al = *(const float4*)&decay[col];
    const float4 om = {1.0f - al.x, 1.0f - al.y, 1.0f - al.z, 1.0f - al.w};
    float4 u = *(const float4*)&carryin[(size_t)unit * OUT_ + col];

    const size_t base = (size_t)(b * T_ + c * LC) * OUT_ + col;
#pragma unroll 4
    for (int t = 0; t < LC; ++t) {
        const ushort4 xv = *(const ushort4*)&Xb[base + (size_t)t * OUT_];
        u.x = fmaf(al.x, u.x, om.x * bf2f(xv.x));
        u.y = fmaf(al.y, u.y, om.y * bf2f(xv.y));
        u.z = fmaf(al.z, u.z, om.z * bf2f(xv.z));
        u.w = fmaf(al.w, u.w, om.w * bf2f(xv.w));
        *(float4*)&out[base + (size_t)t * OUT_] = u;
    }
}

// ---------------------------------------------------------------------------
// Fallback path (ws too small): fp32 GEMM + simple scan, known good.
// ---------------------------------------------------------------------------
__global__ __launch_bounds__(256) void gemm_bias(const float* __restrict__ A,
                                                 const float* __restrict__ W,
                                                 const float* __restrict__ bias,
                                                 float* __restrict__ C) {
    __shared__ float As[16][64 + 4];
    __shared__ float Ws[16][64 + 4];
    const int bm = blockIdx.y * 64;
    const int bn = blockIdx.x * 64;
    const int tid = threadIdx.x;
    const int tx = tid & 15, ty = tid >> 4;
    const int lr = tid >> 2, lc = (tid & 3) << 2;
    float acc[4][4] = {};
    const float* Ap = A + (size_t)(bm + lr) * IN_ + lc;
    const float* Wp = W + (size_t)(bn + lr) * IN_ + lc;
    for (int k0 = 0; k0 < IN_; k0 += 16) {
        const float4 a = *(const float4*)(Ap + k0);
        const float4 w = *(const float4*)(Wp + k0);
        __syncthreads();
        As[lc + 0][lr] = a.x; As[lc + 1][lr] = a.y; As[lc + 2][lr] = a.z; As[lc + 3][lr] = a.w;
        Ws[lc + 0][lr] = w.x; Ws[lc + 1][lr] = w.y; Ws[lc + 2][lr] = w.z; Ws[lc + 3][lr] = w.w;
        __syncthreads();
#pragma unroll
        for (int kk = 0; kk < 16; ++kk) {
            const float4 av = *(const float4*)&As[kk][ty << 2];
            const float4 wv = *(const float4*)&Ws[kk][tx << 2];
            const float a0[4] = {av.x, av.y, av.z, av.w};
            const float w0[4] = {wv.x, wv.y, wv.z, wv.w};
#pragma unroll
            for (int i = 0; i < 4; ++i)
#pragma unroll
                for (int j = 0; j < 4; ++j) acc[i][j] = fmaf(a0[i], w0[j], acc[i][j]);
        }
    }
#pragma unroll
    for (int i = 0; i < 4; ++i) {
        const size_t row = (size_t)(bm + (ty << 2) + i);
#pragma unroll
        for (int j = 0; j < 4; ++j)
            C[row * OUT_ + bn + (tx << 2) + j] = acc[i][j] + bias[bn + (tx << 2) + j];
    }
}

__global__ __launch_bounds__(OUT_) void scan_simple(float* __restrict__ C,
                                                    const float* __restrict__ decay) {
    const int b = blockIdx.x;
    const int o = threadIdx.x;
    const float alpha = decay[o];
    const float om = 1.0f - alpha;
    float u = 0.0f;
    float* p = C + (size_t)b * T_ * OUT_ + o;
    for (int t = 0; t < T_; ++t) {
        const float x = p[(size_t)t * OUT_];
        u = fmaf(alpha, u, om * x);
        p[(size_t)t * OUT_] = u;
    }
}

extern "C" void kernel_launch(void* const* d_in, const int* in_sizes, int n_in,
                              void* d_out, int out_size, void* d_ws, size_t ws_size,
                              hipStream_t stream) {
    const float* inputs = (const float*)d_in[0];
    const float* weight = (const float*)d_in[1];
    const float* bias   = (const float*)d_in[2];
    const float* decay  = (const float*)d_in[3];
    float* out = (float*)d_out;

    // Workspace layout
    const size_t wb_bytes = (size_t)OUT_ * IN_ * 2;             // 512 KB bf16 W
    const size_t ce_bytes = (size_t)B_ * NC * OUT_ * 4;         // 2 MB chunkend
    const size_t ci_bytes = ce_bytes;                           // 2 MB carryin
    const size_t x_bytes  = (size_t)M_ * OUT_ * 2;              // 32 MB bf16 x
    const size_t need = wb_bytes + ce_bytes + ci_bytes + x_bytes;

    if (ws_size >= need) {
        char* w = (char*)d_ws;
        unsigned short* Wb = (unsigned short*)w;
        float* chunkend    = (float*)(w + wb_bytes);
        float* carryin     = (float*)(w + wb_bytes + ce_bytes);
        unsigned short* Xb = (unsigned short*)(w + wb_bytes + ce_bytes + ci_bytes);

        convert_w<<<(OUT_ * IN_ / 4) / 256, 256, 0, stream>>>(weight, Wb);
        gemm_fused<<<M_ / BM, THREADS, 0, stream>>>(inputs, Wb, bias, decay, Xb, chunkend);
        carry_pass<<<B_, OUT_, 0, stream>>>(chunkend, decay, carryin);
        scan_final<<<(B_ * NC) / 4, 256, 0, stream>>>(Xb, decay, carryin, out);
    } else {
        dim3 g(OUT_ / 64, M_ / 64);
        gemm_bias<<<g, 256, 0, stream>>>(inputs, weight, bias, out);
        scan_simple<<<B_, OUT_, 0, stream>>>(out, decay);
    }
}

// Round 7
// 114.124 us; speedup vs baseline: 4.3777x; 1.0223x over previous
//
#include <hip/hip_runtime.h>

// Problem constants
#define B_   32
#define T_   2048
#define IN_  1024
#define OUT_ 256
#define M_   (B_ * T_)   // 65536

// MFMA GEMM tiling: full-N block tile so A is read exactly once.
// BK=32 + global_load_lds for B -> 66 KB LDS, 2 blocks/CU (16 waves/CU).
#define BM 128
#define BN 256
#define BK 32
#define NSTEPS (IN_ / BK)   // 32
#define THREADS 512

// Scan chunking: LC=32 so one BM=128 GEMM block covers exactly 4 chunks.
#define LC 32
#define NC (T_ / LC)        // 64 chunks per batch
#define XPAD 264            // LDS x-tile row pitch (bf16), 528B rows (16B-aligned)

// LDS: staging = 2*(128*32 + 256*32)*2B = 48 KB ; x-tile = 128*264*2 = 66 KB
#define SMEM_BYTES (BM * XPAD * 2)          // 67584, >= 49152 staging
#define ABUF_OFF(c) ((c) * (BM * BK * 2))                   // 8 KB each
#define BBUF_OFF(c) (2 * (BM * BK * 2) + (c) * (BN * BK * 2))  // 16 KB each

typedef __attribute__((ext_vector_type(4))) float f32x4;
typedef __attribute__((ext_vector_type(8))) __bf16 bf16x8;

// fp32 -> bf16 round-to-nearest-even
__device__ __forceinline__ unsigned int f2bf_pk(float a, float b) {
    unsigned int ua = __float_as_uint(a);
    unsigned int ub = __float_as_uint(b);
    ua = (ua + 0x7fffu + ((ua >> 16) & 1u)) >> 16;
    ub = (ub + 0x7fffu + ((ub >> 16) & 1u)) >> 16;
    return ua | (ub << 16);
}
__device__ __forceinline__ unsigned short f2bf1(float a) {
    unsigned int ua = __float_as_uint(a);
    return (unsigned short)((ua + 0x7fffu + ((ua >> 16) & 1u)) >> 16);
}
__device__ __forceinline__ float bf2f(unsigned short s) {
    return __uint_as_float((unsigned int)s << 16);
}

// async global -> LDS, 16B per lane; lds dest = wave-uniform base + lane*16
__device__ __forceinline__ void gload_lds16(const void* g, void* l) {
    __builtin_amdgcn_global_load_lds(
        (const __attribute__((address_space(1))) void*)g,
        (__attribute__((address_space(3))) void*)l, 16, 0, 0);
}

// ---------------------------------------------------------------------------
// One-shot W fp32 -> bf16 into workspace (512 KB).
// ---------------------------------------------------------------------------
__global__ __launch_bounds__(256) void convert_w(const float* __restrict__ W,
                                                 unsigned short* __restrict__ Wb) {
    const int i = blockIdx.x * 256 + threadIdx.x;  // float4 index
    const float4 v = ((const float4*)W)[i];
    uint2 o;
    o.x = f2bf_pk(v.x, v.y);
    o.y = f2bf_pk(v.z, v.w);
    ((uint2*)Wb)[i] = o;
}

// ---------------------------------------------------------------------------
// Fused bf16 MFMA GEMM + chunk-local scan. (Frozen from round 6 — verified.)
// A reg-staged (fp32->bf16 pack), B via global_load_lds with pre-swizzled
// global source (linear LDS dest + XOR'd source granule == XOR'd read, m201).
// Double-buffered, one barrier per K-step, 2 blocks/CU.
// ---------------------------------------------------------------------------
__global__ __launch_bounds__(THREADS, 4) void gemm_fused(
    const float* __restrict__ A, const unsigned short* __restrict__ Wb,
    const float* __restrict__ bias, const float* __restrict__ decay,
    unsigned short* __restrict__ Xb, float* __restrict__ chunkend) {
    __shared__ __align__(16) char smem[SMEM_BYTES];

    const int tid  = threadIdx.x;
    const int lane = tid & 63;
    const int wid  = tid >> 6;
    const int wm   = wid >> 2;     // 0..1  (M direction)
    const int wn   = wid & 3;      // 0..3  (N direction)
    const int l15  = lane & 15;
    const int l4   = lane >> 4;    // 0..3
    const int bm0  = blockIdx.x * BM;

    // --- A staging: 1 granule (8 elems) per thread. q=tid -> row=q>>2, g=q&3.
    const int rowA = tid >> 2;
    const int gA   = tid & 3;
    const float* gsrcA = A + (size_t)(bm0 + rowA) * IN_ + gA * 8;
    const int ldsA = rowA * BK + ((gA ^ (rowA & 3)) << 3);   // elements

    // --- B staging via global_load_lds: 2 instrs/wave, linear LDS dest.
    // LDS granule q = (wid + i*8)*64 + lane -> row=q>>2, g_lin=q&3.
    // Source granule = g_lin ^ (row&3) (involution; read uses same XOR).
    const unsigned short* gsrcB[2];
    int ldsBbase[2];   // byte offset of wave-uniform LDS dest (within Bbuf)
#pragma unroll
    for (int i = 0; i < 2; ++i) {
        const int q = (wid + i * 8) * 64 + lane;
        const int r = q >> 2;
        const int g = (q & 3) ^ (r & 3);
        gsrcB[i] = Wb + (size_t)r * IN_ + g * 8;
        ldsBbase[i] = (wid + i * 8) * 1024;   // bytes; +lane*16 added by HW
    }

    f32x4 acc[4][4] = {};
    float4 a0, a1;

    // --- prologue: stage tile 0 into buf 0 ---
#pragma unroll
    for (int i = 0; i < 2; ++i)
        gload_lds16(gsrcB[i], smem + BBUF_OFF(0) + ldsBbase[i]);
    a0 = *(const float4*)(gsrcA);
    a1 = *(const float4*)(gsrcA + 4);
    {
        int4 w;
        w.x = f2bf_pk(a0.x, a0.y); w.y = f2bf_pk(a0.z, a0.w);
        w.z = f2bf_pk(a1.x, a1.y); w.w = f2bf_pk(a1.z, a1.w);
        *(int4*)(smem + ABUF_OFF(0) + ldsA * 2) = w;
    }
    __syncthreads();

    int cur = 0;
    for (int step = 0; step < NSTEPS; ++step) {
        const int nxt = step + 1;
        if (nxt < NSTEPS) {
            const int k0 = nxt * BK;
#pragma unroll
            for (int i = 0; i < 2; ++i)
                gload_lds16(gsrcB[i] + k0, smem + BBUF_OFF(cur ^ 1) + ldsBbase[i]);
            a0 = *(const float4*)(gsrcA + k0);
            a1 = *(const float4*)(gsrcA + k0 + 4);
        }
        // compute on buf[cur]
        {
            const unsigned short* Ab = (const unsigned short*)(smem + ABUF_OFF(cur));
            const unsigned short* Bb = (const unsigned short*)(smem + BBUF_OFF(cur));
            bf16x8 af[4], bfv[4];
#pragma unroll
            for (int mi = 0; mi < 4; ++mi) {
                const int row = wm * 64 + mi * 16 + l15;
                af[mi] = *(const bf16x8*)&Ab[row * BK + ((l4 ^ (row & 3)) << 3)];
            }
#pragma unroll
            for (int ni = 0; ni < 4; ++ni) {
                const int col = wn * 64 + ni * 16 + l15;
                bfv[ni] = *(const bf16x8*)&Bb[col * BK + ((l4 ^ (col & 3)) << 3)];
            }
#pragma unroll
            for (int mi = 0; mi < 4; ++mi)
#pragma unroll
                for (int ni = 0; ni < 4; ++ni)
                    acc[mi][ni] = __builtin_amdgcn_mfma_f32_16x16x32_bf16(
                        af[mi], bfv[ni], acc[mi][ni], 0, 0, 0);
        }
        if (nxt < NSTEPS) {
            int4 w;
            w.x = f2bf_pk(a0.x, a0.y); w.y = f2bf_pk(a0.z, a0.w);
            w.z = f2bf_pk(a1.x, a1.y); w.w = f2bf_pk(a1.z, a1.w);
            *(int4*)(smem + ABUF_OFF(cur ^ 1) + ldsA * 2) = w;
        }
        __syncthreads();
        cur ^= 1;
    }
    // staging buffers dead now (last iteration ended with a barrier).

    // --- epilogue part 1: x = acc + bias -> bf16 into LDS tile [128][XPAD] ---
    unsigned short* xt = (unsigned short*)smem;
#pragma unroll
    for (int ni = 0; ni < 4; ++ni) {
        const int col = wn * 64 + ni * 16 + l15;
        const float bv = bias[col];
#pragma unroll
        for (int mi = 0; mi < 4; ++mi) {
            const int r0 = wm * 64 + mi * 16 + (l4 << 2);
#pragma unroll
            for (int r = 0; r < 4; ++r)
                xt[(r0 + r) * XPAD + col] = f2bf1(acc[mi][ni][r] + bv);
        }
    }
    __syncthreads();

    const int b  = bm0 >> 11;          // batch index (T = 2048)
    const int c0 = (bm0 >> 5) & 63;    // first chunk id within batch (LC = 32)

    // --- epilogue part 2: dump x tile to global ws (coalesced short8) ---
    {
        const int cr = tid >> 5;             // 0..15
        const int cg = (tid & 31) << 3;      // 8-col granule
#pragma unroll
        for (int it = 0; it < 8; ++it) {
            const int row = it * 16 + cr;
            bf16x8 v = *(const bf16x8*)&xt[row * XPAD + cg];
            *(bf16x8*)&Xb[(size_t)(bm0 + row) * OUT_ + cg] = v;
        }
    }

    // --- epilogue part 3: chunk-local scans (seed 0) -> chunkend ---
    for (int task = tid; task < 4 * OUT_; task += THREADS) {
        const int cl  = task >> 8;       // 0..3 chunk within block
        const int col = task & 255;
        const float alpha = decay[col];
        const float om = 1.0f - alpha;
        float u = 0.0f;
        const unsigned short* p = &xt[(cl * LC) * XPAD + col];
#pragma unroll
        for (int t = 0; t < LC; ++t)
            u = fmaf(alpha, u, om * bf2f(p[t * XPAD]));
        chunkend[(size_t)(b * NC + c0 + cl) * OUT_ + col] = u;
    }
}

// ---------------------------------------------------------------------------
// Carry pass: fold NC=64 chunkends per batch. Restructured: load ALL 64 into
// registers first (64 independent loads in flight -> one HBM latency), then
// run the dependent fmaf chain in-register, then store. Same fp order.
// ---------------------------------------------------------------------------
__global__ __launch_bounds__(OUT_) void carry_pass(const float* __restrict__ chunkend,
                                                   const float* __restrict__ decay,
                                                   float* __restrict__ carryin) {
    const int b = blockIdx.x;
    const int o = threadIdx.x;
    const float alpha = decay[o];
    float aL = alpha;
#pragma unroll
    for (int i = 1; i < LC; ++i) aL *= alpha;   // alpha^LC

    float ce[NC];
#pragma unroll
    for (int c = 0; c < NC; ++c)
        ce[c] = chunkend[(size_t)(b * NC + c) * OUT_ + o];

    float carry = 0.0f;
#pragma unroll
    for (int c = 0; c < NC; ++c) {
        carryin[(size_t)(b * NC + c) * OUT_ + o] = carry;
        carry = fmaf(aL, carry, ce[c]);
    }
}

// ---------------------------------------------------------------------------
// Final scan: 2048 independent (b,chunk) wave-units, 4 cols/thread.
// unroll 8: 8 independent loads in flight per dependent-chain group.
// ---------------------------------------------------------------------------
__global__ __launch_bounds__(256) void scan_final(const unsigned short* __restrict__ Xb,
                                                  const float* __restrict__ decay,
                                                  const float* __restrict__ carryin,
                                                  float* __restrict__ out) {
    const int unit = blockIdx.x * 4 + (threadIdx.x >> 6);  // == b*NC + c
    const int l    = threadIdx.x & 63;
    const int col  = l << 2;
    const int b    = unit >> 6;
    const int c    = unit & 63;

    const float4 al = *(const float4*)&decay[col];
    const float4 om = {1.0f - al.x, 1.0f - al.y, 1.0f - al.z, 1.0f - al.w};
    float4 u = *(const float4*)&carryin[(size_t)unit * OUT_ + col];

    const size_t base = (size_t)(b * T_ + c * LC) * OUT_ + col;
#pragma unroll 8
    for (int t = 0; t < LC; ++t) {
        const ushort4 xv = *(const ushort4*)&Xb[base + (size_t)t * OUT_];
        u.x = fmaf(al.x, u.x, om.x * bf2f(xv.x));
        u.y = fmaf(al.y, u.y, om.y * bf2f(xv.y));
        u.z = fmaf(al.z, u.z, om.z * bf2f(xv.z));
        u.w = fmaf(al.w, u.w, om.w * bf2f(xv.w));
        *(float4*)&out[base + (size_t)t * OUT_] = u;
    }
}

// ---------------------------------------------------------------------------
// Fallback path (ws too small): fp32 GEMM + simple scan, known good.
// ---------------------------------------------------------------------------
__global__ __launch_bounds__(256) void gemm_bias(const float* __restrict__ A,
                                                 const float* __restrict__ W,
                                                 const float* __restrict__ bias,
                                                 float* __restrict__ C) {
    __shared__ float As[16][64 + 4];
    __shared__ float Ws[16][64 + 4];
    const int bm = blockIdx.y * 64;
    const int bn = blockIdx.x * 64;
    const int tid = threadIdx.x;
    const int tx = tid & 15, ty = tid >> 4;
    const int lr = tid >> 2, lc = (tid & 3) << 2;
    float acc[4][4] = {};
    const float* Ap = A + (size_t)(bm + lr) * IN_ + lc;
    const float* Wp = W + (size_t)(bn + lr) * IN_ + lc;
    for (int k0 = 0; k0 < IN_; k0 += 16) {
        const float4 a = *(const float4*)(Ap + k0);
        const float4 w = *(const float4*)(Wp + k0);
        __syncthreads();
        As[lc + 0][lr] = a.x; As[lc + 1][lr] = a.y; As[lc + 2][lr] = a.z; As[lc + 3][lr] = a.w;
        Ws[lc + 0][lr] = w.x; Ws[lc + 1][lr] = w.y; Ws[lc + 2][lr] = w.z; Ws[lc + 3][lr] = w.w;
        __syncthreads();
#pragma unroll
        for (int kk = 0; kk < 16; ++kk) {
            const float4 av = *(const float4*)&As[kk][ty << 2];
            const float4 wv = *(const float4*)&Ws[kk][tx << 2];
            const float a0[4] = {av.x, av.y, av.z, av.w};
            const float w0[4] = {wv.x, wv.y, wv.z, wv.w};
#pragma unroll
            for (int i = 0; i < 4; ++i)
#pragma unroll
                for (int j = 0; j < 4; ++j) acc[i][j] = fmaf(a0[i], w0[j], acc[i][j]);
        }
    }
#pragma unroll
    for (int i = 0; i < 4; ++i) {
        const size_t row = (size_t)(bm + (ty << 2) + i);
#pragma unroll
        for (int j = 0; j < 4; ++j)
            C[row * OUT_ + bn + (tx << 2) + j] = acc[i][j] + bias[bn + (tx << 2) + j];
    }
}

__global__ __launch_bounds__(OUT_) void scan_simple(float* __restrict__ C,
                                                    const float* __restrict__ decay) {
    const int b = blockIdx.x;
    const int o = threadIdx.x;
    const float alpha = decay[o];
    const float om = 1.0f - alpha;
    float u = 0.0f;
    float* p = C + (size_t)b * T_ * OUT_ + o;
    for (int t = 0; t < T_; ++t) {
        const float x = p[(size_t)t * OUT_];
        u = fmaf(alpha, u, om * x);
        p[(size_t)t * OUT_] = u;
    }
}

extern "C" void kernel_launch(void* const* d_in, const int* in_sizes, int n_in,
                              void* d_out, int out_size, void* d_ws, size_t ws_size,
                              hipStream_t stream) {
    const float* inputs = (const float*)d_in[0];
    const float* weight = (const float*)d_in[1];
    const float* bias   = (const float*)d_in[2];
    const float* decay  = (const float*)d_in[3];
    float* out = (float*)d_out;

    // Workspace layout
    const size_t wb_bytes = (size_t)OUT_ * IN_ * 2;             // 512 KB bf16 W
    const size_t ce_bytes = (size_t)B_ * NC * OUT_ * 4;         // 2 MB chunkend
    const size_t ci_bytes = ce_bytes;                           // 2 MB carryin
    const size_t x_bytes  = (size_t)M_ * OUT_ * 2;              // 32 MB bf16 x
    const size_t need = wb_bytes + ce_bytes + ci_bytes + x_bytes;

    if (ws_size >= need) {
        char* w = (char*)d_ws;
        unsigned short* Wb = (unsigned short*)w;
        float* chunkend    = (float*)(w + wb_bytes);
        float* carryin     = (float*)(w + wb_bytes + ce_bytes);
        unsigned short* Xb = (unsigned short*)(w + wb_bytes + ce_bytes + ci_bytes);

        convert_w<<<(OUT_ * IN_ / 4) / 256, 256, 0, stream>>>(weight, Wb);
        gemm_fused<<<M_ / BM, THREADS, 0, stream>>>(inputs, Wb, bias, decay, Xb, chunkend);
        carry_pass<<<B_, OUT_, 0, stream>>>(chunkend, decay, carryin);
        scan_final<<<(B_ * NC) / 4, 256, 0, stream>>>(Xb, decay, carryin, out);
    } else {
        dim3 g(OUT_ / 64, M_ / 64);
        gemm_bias<<<g, 256, 0, stream>>>(inputs, weight, bias, out);
        scan_simple<<<B_, OUT_, 0, stream>>>(out, decay);
    }
}